// Round 11
// baseline (163.561 us; speedup 1.0000x reference)
//
#include <hip/hip_runtime.h>

// GCN layer: out = A_sparse @ (X @ W) + bias
// R11: (1) W^T bf16 prep hoisted to one tiny kernel (kills the 6.8M LDS bank
// conflict cycles from per-block transpose staging + 782x redundant f2bf);
// (2) sortgather back to 8 subs (R9 config, MLP wins) with direct sort into
// in1 (no perm indirection); (3) pass1 buf SoA (2-way LDS writes = free).

#define N_NODES 50000
#define N_EDGES 800000
#define D 128
#define BROWS 66               // rows per bucket
#define NBUCKET 758            // ceil(50000/66)
#define SLOT 1536              // per-bucket capacity (mean 1052, +15 sigma)
#define CHUNK 2048             // edges per pass1 block
#define EPT 8                  // CHUNK/256
#define GEMM_BLOCKS 782        // ceil(50000/64)
#define PASS1_BLOCKS 391       // ceil(800000/2048)

typedef short bf16x8 __attribute__((ext_vector_type(8)));
typedef float f32x4 __attribute__((ext_vector_type(4)));

__device__ inline unsigned short f2bf(float f) {   // RNE f32 -> bf16 bits
    unsigned u = __float_as_uint(f);
    unsigned r = (u + 0x7FFFu + ((u >> 16) & 1u)) >> 16;
    return (unsigned short)r;
}

// ---- ws layout (bytes) ----
// S16:      [0, 12800000)            50000*128*2 bf16
// staging:  [12800000, +9314304)     758*1536 int2 (lrow<<16|col, bits(w))
// gcursor:  [22114304, +3072)        758 bucket cursors (CAS-unpoisoned)
// WT16:     [22117376, +34816)       bf16 W^T padded [128][136]

// ---------------- K0: W^T bf16 prep (once) ----------------
__global__ __launch_bounds__(256) void wprep_kernel(const float* __restrict__ W,
                                                    unsigned short* __restrict__ WT) {
    int idx = blockIdx.x * 256 + threadIdx.x;   // over [k][n], reads coalesced
    if (idx < 128 * 128) {
        int k = idx >> 7, n = idx & 127;
        WT[n * 136 + k] = f2bf(W[idx]);
    }
}

// ---------------- K1: fused gemm (blocks < GEMM_BLOCKS) + pass1 ------------
__global__ __launch_bounds__(256) void fused_kernel(const float* __restrict__ X,
                                                    const unsigned short* __restrict__ WT,
                                                    unsigned short* __restrict__ S16,
                                                    const int* __restrict__ ei,
                                                    const float* __restrict__ ew,
                                                    int* __restrict__ gcursor,
                                                    int2* __restrict__ staging) {
    __shared__ __align__(16) char shmem[52224];
    const int t = threadIdx.x;
    const int lane = t & 63, wid = t >> 6;

    if (blockIdx.x < GEMM_BLOCKS) {
        // ================= GEMM: S16 = bf16(X @ W) =================
        unsigned short* wt = (unsigned short*)shmem;            // [128][136]
        unsigned short* xt = (unsigned short*)(shmem + 34816);  // [64][136]
        const int row0 = blockIdx.x * 64;

        // stage W^T bf16: pure uint4 memcpy, conflict-free, no converts
        const uint4* WTg = (const uint4*)WT;
        uint4* wl = (uint4*)wt;
#pragma unroll
        for (int i = 0; i < 9; ++i) {
            int idx = t + 256 * i;                // 2176 uint4 total
            if (idx < 2176) wl[idx] = WTg[idx];
        }
        const float4* X4 = (const float4*)X;
#pragma unroll
        for (int i = 0; i < 8; ++i) {
            int idx4 = t + 256 * i;
            int r = idx4 >> 5, c4 = idx4 & 31;
            int gr = row0 + r;
            float4 v = make_float4(0.f, 0.f, 0.f, 0.f);
            if (gr < N_NODES) v = X4[gr * 32 + c4];
            ushort4 u = make_ushort4(f2bf(v.x), f2bf(v.y), f2bf(v.z), f2bf(v.w));
            *(ushort4*)&xt[r * 136 + c4 * 4] = u;
        }
        __syncthreads();

        const int m = lane & 15;
        const int q = lane >> 4;
        const int rbase = wid * 16;

        f32x4 acc[8];
#pragma unroll
        for (int nt = 0; nt < 8; ++nt) acc[nt] = (f32x4){0.f, 0.f, 0.f, 0.f};
#pragma unroll
        for (int ks = 0; ks < 4; ++ks) {
            bf16x8 a = *(const bf16x8*)&xt[(rbase + m) * 136 + ks * 32 + q * 8];
#pragma unroll
            for (int nt = 0; nt < 8; ++nt) {
                bf16x8 b = *(const bf16x8*)&wt[(nt * 16 + m) * 136 + ks * 32 + q * 8];
                acc[nt] = __builtin_amdgcn_mfma_f32_16x16x32_bf16(a, b, acc[nt], 0, 0, 0);
            }
        }
        __syncthreads();
#pragma unroll
        for (int nt = 0; nt < 8; ++nt) {
            int col = nt * 16 + m;
#pragma unroll
            for (int r = 0; r < 4; ++r) {
                int rl = rbase + q * 4 + r;
                xt[rl * 136 + col] = f2bf(acc[nt][r]);
            }
        }
        __syncthreads();
#pragma unroll
        for (int i = 0; i < 4; ++i) {
            int id = t + 256 * i;
            int r = id >> 4, c8 = (id & 15) * 8;
            int gr = row0 + r;
            if (gr < N_NODES)
                *(uint4*)&S16[gr * 128 + c8] = *(const uint4*)&xt[r * 136 + c8];
        }
    } else {
        // ================= PASS1: bucket multisplit (758 buckets) =========
        int* bufx            = (int*)shmem;                         // [2048] 8KB
        int* bufw            = (int*)(shmem + 8192);                // [2048] 8KB
        unsigned short* bof  = (unsigned short*)(shmem + 16384);    // [2048] 4KB
        int* hist            = (int*)(shmem + 20480);               // [768]
        int* lcur            = (int*)(shmem + 23552);               // [768]
        int* bmg             = (int*)(shmem + 26624);               // [768]
        int* wsum            = (int*)(shmem + 29696);               // [4]
        const int base = (blockIdx.x - GEMM_BLOCKS) * CHUNK;

        hist[t] = 0;
        hist[t + 256] = 0;
        hist[t + 512] = 0;
        __syncthreads();

        int rows[EPT];
        int bkt[EPT];
#pragma unroll
        for (int i = 0; i < EPT; ++i) {
            int e = base + t + 256 * i;
            rows[i] = (e < N_EDGES) ? ei[e] : -1;
            bkt[i] = (rows[i] >= 0) ? (rows[i] / BROWS) : -1;
            if (bkt[i] >= 0) atomicAdd(&hist[bkt[i]], 1);
        }
        __syncthreads();

        // three-phase wave-shfl exclusive scan of hist[768]
        int run = 0, exv[3], vv[3];
#pragma unroll
        for (int ph = 0; ph < 3; ++ph) {
            int v = hist[ph * 256 + t];
            vv[ph] = v;
            int incl = v;
#pragma unroll
            for (int off = 1; off < 64; off <<= 1) {
                int x = __shfl_up(incl, off, 64);
                if (lane >= off) incl += x;
            }
            if (lane == 63) wsum[wid] = incl;
            __syncthreads();
            int pre = 0, tot = 0;
#pragma unroll
            for (int w = 0; w < 4; ++w) {
                int x = wsum[w];
                if (w < wid) pre += x;
                tot += x;
            }
            exv[ph] = run + incl - v + pre;
            run += tot;
            __syncthreads();
        }
        const int total = run;
        lcur[t] = exv[0];
        lcur[t + 256] = exv[1];
        lcur[t + 512] = exv[2];
#pragma unroll
        for (int ph = 0; ph < 3; ++ph) {
            int b = ph * 256 + t;
            if (b < NBUCKET) {
                int v = vv[ph];
                if (v > 0) {
                    // lazy un-poison: harness fills ws with 0xAA; first toucher
                    // CASes poison->0, then everyone atomically reserves space.
                    atomicCAS((unsigned*)&gcursor[b], 0xAAAAAAAAu, 0u);
                    int gb = atomicAdd(&gcursor[b], v);
                    bmg[b] = b * SLOT + gb - exv[ph];
                }
            }
        }
        __syncthreads();

        // local reorder into bucket-contiguous LDS (SoA: 4B writes, 2-way max)
#pragma unroll
        for (int i = 0; i < EPT; ++i) {
            if (rows[i] >= 0) {
                int e = base + t + 256 * i;
                int col = ei[N_EDGES + e];
                float w = ew[e];
                int b = bkt[i];
                int lp = atomicAdd(&lcur[b], 1);
                int lrow = rows[i] - b * BROWS;     // 0..65
                bufx[lp] = (int)(((unsigned)lrow << 16) | (unsigned)col);
                bufw[lp] = __float_as_int(w);
                bof[lp] = (unsigned short)b;
            }
        }
        __syncthreads();

        // coalesced sweep: consecutive lp in same bucket -> consecutive gaddr
        for (int lp = t; lp < total; lp += 256) {
            int b = bof[lp];
            int g = bmg[b] + lp;
            if (g < (b + 1) * SLOT)
                staging[g] = make_int2(bufx[lp], bufw[lp]);   // overflow guard
        }
    }
}

// ---------------- K2: fused per-bucket sort + gather ----------------
// One 512-thread block per 66-row bucket. Phase A: bucket -> in0, int-atomic
// hist by local row, wave scan, sort directly into in1 (no perm indirection).
// Phase B: wave wv does rows wv, wv+8, ...; 8 subs of 8 lanes = 8 edges in
// flight; q=lane&7 owns 16 dims (2x uint4); 3-round shfl_xor; +bias store.
__global__ __launch_bounds__(512) void sortgather_kernel(const unsigned short* __restrict__ S16,
                                                         const int* __restrict__ gcursor,
                                                         const int2* __restrict__ staging,
                                                         const float* __restrict__ bias,
                                                         float* __restrict__ out) {
    __shared__ int2 in0[SLOT];              // 12288 B
    __shared__ int2 in1[SLOT];              // 12288 B
    __shared__ int hist[128];               // entries >= BROWS stay 0
    __shared__ int exs[128];
    __shared__ int lcur[128];
    __shared__ int wsum[2];
    const int t = threadIdx.x;
    const int b = blockIdx.x;
    const int lane = t & 63;
    int cnt = gcursor[b];
    if (cnt > SLOT) cnt = SLOT;

    if (t < 128) hist[t] = 0;
    __syncthreads();

    for (int i = t; i < cnt; i += 512) {
        int2 v = staging[b * SLOT + i];
        in0[i] = v;
        atomicAdd(&hist[((unsigned)v.x >> 16) & 127u], 1);
    }
    __syncthreads();

    // scan hist[128] using threads 0..127
    int v = 0, incl = 0;
    if (t < 128) {
        v = hist[t];
        incl = v;
#pragma unroll
        for (int off = 1; off < 64; off <<= 1) {
            int x = __shfl_up(incl, off, 64);
            if (lane >= off) incl += x;
        }
        if (lane == 63) wsum[t >> 6] = incl;
    }
    __syncthreads();
    if (t < 128) {
        int pre = (t >= 64) ? wsum[0] : 0;
        int ex = incl - v + pre;
        exs[t] = ex;
        lcur[t] = ex;
    }
    __syncthreads();

    // sort payload directly into in1 (row-contiguous)
    for (int i = t; i < cnt; i += 512) {
        int2 e = in0[i];
        int lr = (int)(((unsigned)e.x >> 16) & 127u);
        int p = atomicAdd(&lcur[lr], 1);
        in1[p] = e;
    }
    __syncthreads();

    // gather
    const int wv = t >> 6;                   // 0..7
    const int sub = lane >> 3;               // 0..7 edge sub-streams
    const int q = lane & 7;                  // owns dims q*16..q*16+15
    const uint4* S4 = (const uint4*)S16;     // row stride: 16 uint4
    const float4* bias4 = (const float4*)bias;
    float4 bb[4];
#pragma unroll
    for (int j = 0; j < 4; ++j) bb[j] = bias4[q * 4 + j];

    for (int rr = wv; rr < BROWS; rr += 8) {
        int beg = exs[rr];
        int end = beg + hist[rr];
        float acc[16];
#pragma unroll
        for (int i = 0; i < 16; ++i) acc[i] = 0.f;
        for (int p = beg + sub; p < end; p += 8) {
            int2 cw = in1[p];                // broadcast across 8 lanes
            float w = __int_as_float(cw.y);
            int col = cw.x & 0xFFFF;
            uint4 v0 = S4[col * 16 + q * 2];
            uint4 v1 = S4[col * 16 + q * 2 + 1];
            acc[0]  += __uint_as_float(v0.x << 16) * w;
            acc[1]  += __uint_as_float(v0.x & 0xFFFF0000u) * w;
            acc[2]  += __uint_as_float(v0.y << 16) * w;
            acc[3]  += __uint_as_float(v0.y & 0xFFFF0000u) * w;
            acc[4]  += __uint_as_float(v0.z << 16) * w;
            acc[5]  += __uint_as_float(v0.z & 0xFFFF0000u) * w;
            acc[6]  += __uint_as_float(v0.w << 16) * w;
            acc[7]  += __uint_as_float(v0.w & 0xFFFF0000u) * w;
            acc[8]  += __uint_as_float(v1.x << 16) * w;
            acc[9]  += __uint_as_float(v1.x & 0xFFFF0000u) * w;
            acc[10] += __uint_as_float(v1.y << 16) * w;
            acc[11] += __uint_as_float(v1.y & 0xFFFF0000u) * w;
            acc[12] += __uint_as_float(v1.z << 16) * w;
            acc[13] += __uint_as_float(v1.z & 0xFFFF0000u) * w;
            acc[14] += __uint_as_float(v1.w << 16) * w;
            acc[15] += __uint_as_float(v1.w & 0xFFFF0000u) * w;
        }
#pragma unroll
        for (int i = 0; i < 16; ++i) acc[i] += __shfl_xor(acc[i], 8, 64);
#pragma unroll
        for (int i = 0; i < 16; ++i) acc[i] += __shfl_xor(acc[i], 16, 64);
#pragma unroll
        for (int i = 0; i < 16; ++i) acc[i] += __shfl_xor(acc[i], 32, 64);
        int gr = b * BROWS + rr;
        if (sub == 0 && gr < N_NODES) {
#pragma unroll
            for (int j = 0; j < 4; ++j) {
                float4 o = make_float4(acc[4 * j + 0] + bb[j].x, acc[4 * j + 1] + bb[j].y,
                                       acc[4 * j + 2] + bb[j].z, acc[4 * j + 3] + bb[j].w);
                ((float4*)out)[gr * 32 + q * 4 + j] = o;
            }
        }
    }
}

extern "C" void kernel_launch(void* const* d_in, const int* in_sizes, int n_in,
                              void* d_out, int out_size, void* d_ws, size_t ws_size,
                              hipStream_t stream) {
    const float* X    = (const float*)d_in[0];
    const int*   ei   = (const int*)d_in[1];
    const float* ew   = (const float*)d_in[2];
    const float* W    = (const float*)d_in[3];
    const float* bias = (const float*)d_in[4];
    float* out = (float*)d_out;

    char* ws = (char*)d_ws;
    unsigned short* S16 = (unsigned short*)(ws);
    int2* staging = (int2*)(ws + 12800000);
    int*  gcursor = (int*)(ws + 22114304);
    unsigned short* WT16 = (unsigned short*)(ws + 22117376);

    wprep_kernel<<<64, 256, 0, stream>>>(W, WT16);
    fused_kernel<<<GEMM_BLOCKS + PASS1_BLOCKS, 256, 0, stream>>>(X, WT16, S16, ei, ew,
                                                                 gcursor, staging);
    sortgather_kernel<<<NBUCKET, 512, 0, stream>>>(S16, gcursor, staging, bias, out);
}

// Round 12
// 146.140 us; speedup vs baseline: 1.1192x; 1.1192x over previous
//
#include <hip/hip_runtime.h>

// GCN layer: out = A_sparse @ (X @ W) + bias
// R12: pass1 atomic de-serialization: gcursor padded 1/cacheline (758 lines
// vs 12), CAS dropped (cursors zeroed in wprep), CHUNK 2048->4096 (196 pass1
// blocks, ~148K bucket atomics vs 276K, longer coalesced staging runs).

#define N_NODES 50000
#define N_EDGES 800000
#define D 128
#define BROWS 66               // rows per bucket
#define NBUCKET 758            // ceil(50000/66)
#define SLOT 1536              // per-bucket capacity (mean 1052, +15 sigma)
#define CHUNK 4096             // edges per pass1 block
#define EPT 16                 // CHUNK/256
#define GEMM_BLOCKS 782        // ceil(50000/64)
#define PASS1_BLOCKS 196       // ceil(800000/4096)
#define CSTRIDE 16             // gcursor padding: 16 ints = 64B per cursor

typedef short bf16x8 __attribute__((ext_vector_type(8)));
typedef float f32x4 __attribute__((ext_vector_type(4)));

__device__ inline unsigned short f2bf(float f) {   // RNE f32 -> bf16 bits
    unsigned u = __float_as_uint(f);
    unsigned r = (u + 0x7FFFu + ((u >> 16) & 1u)) >> 16;
    return (unsigned short)r;
}

// ---- ws layout (bytes) ----
// S16:      [0, 12800000)            50000*128*2 bf16
// staging:  [12800000, +9314304)     758*1536 int2 (lrow<<16|col, bits(w))
// gcursor:  [22114304, +48512)       758 cursors, 64B apart
// WT16:     [22162816, +34816)       bf16 W^T padded [128][136]

// ---------------- K0: W^T bf16 prep + cursor zero (once) ----------------
__global__ __launch_bounds__(256) void wprep_kernel(const float* __restrict__ W,
                                                    unsigned short* __restrict__ WT,
                                                    int* __restrict__ gcursor) {
    int idx = blockIdx.x * 256 + threadIdx.x;
    if (idx < 128 * 128) {
        int k = idx >> 7, n = idx & 127;
        WT[n * 136 + k] = f2bf(W[idx]);
    }
    if (idx < NBUCKET * CSTRIDE) gcursor[idx] = 0;
}

// ---------------- K1: fused gemm (blocks < GEMM_BLOCKS) + pass1 ------------
__global__ __launch_bounds__(256) void fused_kernel(const float* __restrict__ X,
                                                    const unsigned short* __restrict__ WT,
                                                    unsigned short* __restrict__ S16,
                                                    const int* __restrict__ ei,
                                                    const float* __restrict__ ew,
                                                    int* __restrict__ gcursor,
                                                    int2* __restrict__ staging) {
    __shared__ __align__(16) char shmem[52224];
    const int t = threadIdx.x;
    const int lane = t & 63, wid = t >> 6;

    if (blockIdx.x < GEMM_BLOCKS) {
        // ================= GEMM: S16 = bf16(X @ W) =================
        unsigned short* wt = (unsigned short*)shmem;            // [128][136]
        unsigned short* xt = (unsigned short*)(shmem + 34816);  // [64][136]
        const int row0 = blockIdx.x * 64;

        // stage W^T bf16: pure uint4 memcpy, conflict-free, no converts
        const uint4* WTg = (const uint4*)WT;
        uint4* wl = (uint4*)wt;
#pragma unroll
        for (int i = 0; i < 9; ++i) {
            int idx = t + 256 * i;                // 2176 uint4 total
            if (idx < 2176) wl[idx] = WTg[idx];
        }
        const float4* X4 = (const float4*)X;
#pragma unroll
        for (int i = 0; i < 8; ++i) {
            int idx4 = t + 256 * i;
            int r = idx4 >> 5, c4 = idx4 & 31;
            int gr = row0 + r;
            float4 v = make_float4(0.f, 0.f, 0.f, 0.f);
            if (gr < N_NODES) v = X4[gr * 32 + c4];
            ushort4 u = make_ushort4(f2bf(v.x), f2bf(v.y), f2bf(v.z), f2bf(v.w));
            *(ushort4*)&xt[r * 136 + c4 * 4] = u;
        }
        __syncthreads();

        const int m = lane & 15;
        const int q = lane >> 4;
        const int rbase = wid * 16;

        f32x4 acc[8];
#pragma unroll
        for (int nt = 0; nt < 8; ++nt) acc[nt] = (f32x4){0.f, 0.f, 0.f, 0.f};
#pragma unroll
        for (int ks = 0; ks < 4; ++ks) {
            bf16x8 a = *(const bf16x8*)&xt[(rbase + m) * 136 + ks * 32 + q * 8];
#pragma unroll
            for (int nt = 0; nt < 8; ++nt) {
                bf16x8 b = *(const bf16x8*)&wt[(nt * 16 + m) * 136 + ks * 32 + q * 8];
                acc[nt] = __builtin_amdgcn_mfma_f32_16x16x32_bf16(a, b, acc[nt], 0, 0, 0);
            }
        }
        __syncthreads();
#pragma unroll
        for (int nt = 0; nt < 8; ++nt) {
            int col = nt * 16 + m;
#pragma unroll
            for (int r = 0; r < 4; ++r) {
                int rl = rbase + q * 4 + r;
                xt[rl * 136 + col] = f2bf(acc[nt][r]);
            }
        }
        __syncthreads();
#pragma unroll
        for (int i = 0; i < 4; ++i) {
            int id = t + 256 * i;
            int r = id >> 4, c8 = (id & 15) * 8;
            int gr = row0 + r;
            if (gr < N_NODES)
                *(uint4*)&S16[gr * 128 + c8] = *(const uint4*)&xt[r * 136 + c8];
        }
    } else {
        // ================= PASS1: bucket multisplit (758 buckets) =========
        int* bufx            = (int*)shmem;                         // [4096] 16KB
        int* bufw            = (int*)(shmem + 16384);               // [4096] 16KB
        unsigned short* bof  = (unsigned short*)(shmem + 32768);    // [4096] 8KB
        int* hist            = (int*)(shmem + 40960);               // [768]
        int* lcur            = (int*)(shmem + 44032);               // [768]
        int* bmg             = (int*)(shmem + 47104);               // [768]
        int* wsum            = (int*)(shmem + 50176);               // [4]
        const int base = (blockIdx.x - GEMM_BLOCKS) * CHUNK;

        hist[t] = 0;
        hist[t + 256] = 0;
        hist[t + 512] = 0;
        __syncthreads();

        int rows[EPT];
        int bkt[EPT];
#pragma unroll
        for (int i = 0; i < EPT; ++i) {
            int e = base + t + 256 * i;
            rows[i] = (e < N_EDGES) ? ei[e] : -1;
            bkt[i] = (rows[i] >= 0) ? (rows[i] / BROWS) : -1;
            if (bkt[i] >= 0) atomicAdd(&hist[bkt[i]], 1);
        }
        __syncthreads();

        // three-phase wave-shfl exclusive scan of hist[768]
        int run = 0, exv[3], vv[3];
#pragma unroll
        for (int ph = 0; ph < 3; ++ph) {
            int v = hist[ph * 256 + t];
            vv[ph] = v;
            int incl = v;
#pragma unroll
            for (int off = 1; off < 64; off <<= 1) {
                int x = __shfl_up(incl, off, 64);
                if (lane >= off) incl += x;
            }
            if (lane == 63) wsum[wid] = incl;
            __syncthreads();
            int pre = 0, tot = 0;
#pragma unroll
            for (int w = 0; w < 4; ++w) {
                int x = wsum[w];
                if (w < wid) pre += x;
                tot += x;
            }
            exv[ph] = run + incl - v + pre;
            run += tot;
            __syncthreads();
        }
        const int total = run;
        lcur[t] = exv[0];
        lcur[t + 256] = exv[1];
        lcur[t + 512] = exv[2];
#pragma unroll
        for (int ph = 0; ph < 3; ++ph) {
            int b = ph * 256 + t;
            if (b < NBUCKET) {
                int v = vv[ph];
                if (v > 0) {
                    int gb = atomicAdd(&gcursor[b * CSTRIDE], v);
                    bmg[b] = b * SLOT + gb - exv[ph];
                }
            }
        }
        __syncthreads();

        // local reorder into bucket-contiguous LDS (SoA: 4B writes, 2-way max)
#pragma unroll
        for (int i = 0; i < EPT; ++i) {
            if (rows[i] >= 0) {
                int e = base + t + 256 * i;
                int col = ei[N_EDGES + e];
                float w = ew[e];
                int b = bkt[i];
                int lp = atomicAdd(&lcur[b], 1);
                int lrow = rows[i] - b * BROWS;     // 0..65
                bufx[lp] = (int)(((unsigned)lrow << 16) | (unsigned)col);
                bufw[lp] = __float_as_int(w);
                bof[lp] = (unsigned short)b;
            }
        }
        __syncthreads();

        // coalesced sweep: consecutive lp in same bucket -> consecutive gaddr
        for (int lp = t; lp < total; lp += 256) {
            int b = bof[lp];
            int g = bmg[b] + lp;
            if (g < (b + 1) * SLOT)
                staging[g] = make_int2(bufx[lp], bufw[lp]);   // overflow guard
        }
    }
}

// ---------------- K2: fused per-bucket sort + gather ----------------
// One 512-thread block per 66-row bucket. Phase A: bucket -> in0, int-atomic
// hist by local row, wave scan, sort directly into in1 (no perm indirection).
// Phase B: wave wv does rows wv, wv+8, ...; 8 subs of 8 lanes = 8 edges in
// flight; q=lane&7 owns 16 dims (2x uint4); 3-round shfl_xor; +bias store.
__global__ __launch_bounds__(512) void sortgather_kernel(const unsigned short* __restrict__ S16,
                                                         const int* __restrict__ gcursor,
                                                         const int2* __restrict__ staging,
                                                         const float* __restrict__ bias,
                                                         float* __restrict__ out) {
    __shared__ int2 in0[SLOT];              // 12288 B
    __shared__ int2 in1[SLOT];              // 12288 B
    __shared__ int hist[128];               // entries >= BROWS stay 0
    __shared__ int exs[128];
    __shared__ int lcur[128];
    __shared__ int wsum[2];
    const int t = threadIdx.x;
    const int b = blockIdx.x;
    const int lane = t & 63;
    int cnt = gcursor[b * CSTRIDE];
    if (cnt > SLOT) cnt = SLOT;

    if (t < 128) hist[t] = 0;
    __syncthreads();

    for (int i = t; i < cnt; i += 512) {
        int2 v = staging[b * SLOT + i];
        in0[i] = v;
        atomicAdd(&hist[((unsigned)v.x >> 16) & 127u], 1);
    }
    __syncthreads();

    // scan hist[128] using threads 0..127
    int v = 0, incl = 0;
    if (t < 128) {
        v = hist[t];
        incl = v;
#pragma unroll
        for (int off = 1; off < 64; off <<= 1) {
            int x = __shfl_up(incl, off, 64);
            if (lane >= off) incl += x;
        }
        if (lane == 63) wsum[t >> 6] = incl;
    }
    __syncthreads();
    if (t < 128) {
        int pre = (t >= 64) ? wsum[0] : 0;
        int ex = incl - v + pre;
        exs[t] = ex;
        lcur[t] = ex;
    }
    __syncthreads();

    // sort payload directly into in1 (row-contiguous)
    for (int i = t; i < cnt; i += 512) {
        int2 e = in0[i];
        int lr = (int)(((unsigned)e.x >> 16) & 127u);
        int p = atomicAdd(&lcur[lr], 1);
        in1[p] = e;
    }
    __syncthreads();

    // gather
    const int wv = t >> 6;                   // 0..7
    const int sub = lane >> 3;               // 0..7 edge sub-streams
    const int q = lane & 7;                  // owns dims q*16..q*16+15
    const uint4* S4 = (const uint4*)S16;     // row stride: 16 uint4
    const float4* bias4 = (const float4*)bias;
    float4 bb[4];
#pragma unroll
    for (int j = 0; j < 4; ++j) bb[j] = bias4[q * 4 + j];

    for (int rr = wv; rr < BROWS; rr += 8) {
        int beg = exs[rr];
        int end = beg + hist[rr];
        float acc[16];
#pragma unroll
        for (int i = 0; i < 16; ++i) acc[i] = 0.f;
        for (int p = beg + sub; p < end; p += 8) {
            int2 cw = in1[p];                // broadcast across 8 lanes
            float w = __int_as_float(cw.y);
            int col = cw.x & 0xFFFF;
            uint4 v0 = S4[col * 16 + q * 2];
            uint4 v1 = S4[col * 16 + q * 2 + 1];
            acc[0]  += __uint_as_float(v0.x << 16) * w;
            acc[1]  += __uint_as_float(v0.x & 0xFFFF0000u) * w;
            acc[2]  += __uint_as_float(v0.y << 16) * w;
            acc[3]  += __uint_as_float(v0.y & 0xFFFF0000u) * w;
            acc[4]  += __uint_as_float(v0.z << 16) * w;
            acc[5]  += __uint_as_float(v0.z & 0xFFFF0000u) * w;
            acc[6]  += __uint_as_float(v0.w << 16) * w;
            acc[7]  += __uint_as_float(v0.w & 0xFFFF0000u) * w;
            acc[8]  += __uint_as_float(v1.x << 16) * w;
            acc[9]  += __uint_as_float(v1.x & 0xFFFF0000u) * w;
            acc[10] += __uint_as_float(v1.y << 16) * w;
            acc[11] += __uint_as_float(v1.y & 0xFFFF0000u) * w;
            acc[12] += __uint_as_float(v1.z << 16) * w;
            acc[13] += __uint_as_float(v1.z & 0xFFFF0000u) * w;
            acc[14] += __uint_as_float(v1.w << 16) * w;
            acc[15] += __uint_as_float(v1.w & 0xFFFF0000u) * w;
        }
#pragma unroll
        for (int i = 0; i < 16; ++i) acc[i] += __shfl_xor(acc[i], 8, 64);
#pragma unroll
        for (int i = 0; i < 16; ++i) acc[i] += __shfl_xor(acc[i], 16, 64);
#pragma unroll
        for (int i = 0; i < 16; ++i) acc[i] += __shfl_xor(acc[i], 32, 64);
        int gr = b * BROWS + rr;
        if (sub == 0 && gr < N_NODES) {
#pragma unroll
            for (int j = 0; j < 4; ++j) {
                float4 o = make_float4(acc[4 * j + 0] + bb[j].x, acc[4 * j + 1] + bb[j].y,
                                       acc[4 * j + 2] + bb[j].z, acc[4 * j + 3] + bb[j].w);
                ((float4*)out)[gr * 32 + q * 4 + j] = o;
            }
        }
    }
}

extern "C" void kernel_launch(void* const* d_in, const int* in_sizes, int n_in,
                              void* d_out, int out_size, void* d_ws, size_t ws_size,
                              hipStream_t stream) {
    const float* X    = (const float*)d_in[0];
    const int*   ei   = (const int*)d_in[1];
    const float* ew   = (const float*)d_in[2];
    const float* W    = (const float*)d_in[3];
    const float* bias = (const float*)d_in[4];
    float* out = (float*)d_out;

    char* ws = (char*)d_ws;
    unsigned short* S16 = (unsigned short*)(ws);
    int2* staging = (int2*)(ws + 12800000);
    int*  gcursor = (int*)(ws + 22114304);
    unsigned short* WT16 = (unsigned short*)(ws + 22162816);

    wprep_kernel<<<64, 256, 0, stream>>>(W, WT16, gcursor);
    fused_kernel<<<GEMM_BLOCKS + PASS1_BLOCKS, 256, 0, stream>>>(X, WT16, S16, ei, ew,
                                                                 gcursor, staging);
    sortgather_kernel<<<NBUCKET, 512, 0, stream>>>(S16, gcursor, staging, bias, out);
}